// Round 10
// baseline (703.417 us; speedup 1.0000x reference)
//
#include <hip/hip_runtime.h>

#define B_ 32
#define S_ 2048
#define H_ 1024

typedef __attribute__((ext_vector_type(8))) short short8;
typedef __attribute__((ext_vector_type(4))) float f32x4;
typedef __attribute__((ext_vector_type(4))) unsigned short u16x4;

__device__ __forceinline__ unsigned short f2bf(float f) {
    unsigned u = __builtin_bit_cast(unsigned, f);
    u += 0x7FFFu + ((u >> 16) & 1u);
    return (unsigned short)(u >> 16);
}
__device__ __forceinline__ unsigned pk2(float x, float y) {
    return (unsigned)f2bf(x) | ((unsigned)f2bf(y) << 16);
}
__device__ __forceinline__ float bf2f(unsigned short u) {
    unsigned x = ((unsigned)u) << 16;
    return __builtin_bit_cast(float, x);
}
__device__ __forceinline__ void gload16(const void* g, void* l) {
    __builtin_amdgcn_global_load_lds((const __attribute__((address_space(1))) void*)g,
                                     (__attribute__((address_space(3))) void*)l, 16, 0, 0);
}

#define WAITV(nstr) asm volatile("s_waitcnt vmcnt(" nstr ")" ::: "memory")

// ---------- enc fp32 -> bf16 (row-major) ----------
__global__ void k_cvt(const float* __restrict__ in, uint4* __restrict__ out, int ngroups) {
    int i = blockIdx.x * blockDim.x + threadIdx.x;
    int stride = gridDim.x * blockDim.x;
    for (; i < ngroups; i += stride) {
        const float4* p = (const float4*)in + (size_t)i * 2;
        float4 x = p[0], y = p[1];
        out[i] = make_uint4(pk2(x.x, x.y), pk2(x.z, x.w), pk2(y.x, y.y), pk2(y.z, y.w));
    }
}

// ---------- prep: Wh (K,N) fp32 -> WhT (N,K) bf16 ----------
__global__ void k_whT(const float* __restrict__ Wh, unsigned short* __restrict__ whT) {
    __shared__ float tile[64][65];
    int k0 = blockIdx.x * 64, n0 = blockIdx.y * 64;
    int tx = threadIdx.x, ty = threadIdx.y; // (64,4)
    #pragma unroll
    for (int i = 0; i < 16; ++i) {
        int r = ty + i * 4;
        tile[r][tx] = Wh[(size_t)(k0 + r) * H_ + n0 + tx];
    }
    __syncthreads();
    #pragma unroll
    for (int i = 0; i < 16; ++i) {
        int r = ty + i * 4;
        whT[(size_t)(n0 + r) * H_ + k0 + tx] = f2bf(tile[tx][r]);
    }
}

// ---------- prep: decp for 2 batches/block (Ws read 16x = 64MB) ----------
__global__ void k_decp2(const float* __restrict__ ds, const float* __restrict__ Ws,
                        const float* __restrict__ bs, const float* __restrict__ bh,
                        float* __restrict__ decp) {
    __shared__ float sd[2][1024];
    int tid = threadIdx.x;
    int n = blockIdx.x * 256 + tid;
    int b0 = blockIdx.y * 2;
    for (int i = tid; i < 2048; i += 256) sd[i >> 10][i & 1023] = ds[b0 * H_ + i];
    __syncthreads();
    float a0 = 0.f, a1 = 0.f;
    #pragma unroll 4
    for (int k = 0; k < H_; ++k) {
        float w = Ws[(size_t)k * H_ + n];
        a0 += sd[0][k] * w;
        a1 += sd[1][k] * w;
    }
    float bias = bs[n] + bh[n];
    decp[(b0 + 0) * H_ + n] = a0 + bias;
    decp[(b0 + 1) * H_ + n] = a1 + bias;
}

// ---------- prep: covp[b] = cov[b]@Wc + bc ----------
__global__ void k_covp(const float* __restrict__ cov, const float* __restrict__ Wc,
                       const float* __restrict__ bc, float* __restrict__ covp) {
    int b = blockIdx.x, t = threadIdx.x;
    float p = 0.f;
    for (int s = t; s < S_; s += 256) p += cov[b * S_ + s] * Wc[s];
    for (int off = 32; off; off >>= 1) p += __shfl_down(p, off);
    __shared__ float w[4];
    if ((t & 63) == 0) w[t >> 6] = p;
    __syncthreads();
    if (t == 0) covp[b] = w[0] + w[1] + w[2] + w[3] + bc[0];
}

// ---------- shared epilogue: tanh + V-dot + 16-lane reduce + atomicAdd ----------
// wave tile 64x64 at (row0 + wm*64, n0 + wn*64); acc[m][n] 16x16 frags.
__device__ __forceinline__ void score_epilogue(
    f32x4 acc[4][4], int n0, int wm, int wn, int lane, size_t row0,
    const float* __restrict__ decp, const float* __restrict__ covp,
    const float* __restrict__ V, float* __restrict__ scores)
{
    int colb = n0 + wn * 64 + (lane & 15);
    size_t rowg = row0 + (size_t)wm * 64;
    int b = (int)(rowg >> 11); // / S_
    float cb = covp[b];
    float vv[4], dp[4];
    #pragma unroll
    for (int n = 0; n < 4; ++n) {
        int c = colb + n * 16;
        vv[n] = V[c];
        dp[n] = decp[b * H_ + c] + cb;
    }
    #pragma unroll
    for (int m = 0; m < 4; ++m) {
        float rs[4] = {0.f, 0.f, 0.f, 0.f};
        #pragma unroll
        for (int n = 0; n < 4; ++n) {
            f32x4 A = acc[m][n];
            #pragma unroll
            for (int j = 0; j < 4; ++j) {
                float x = A[j] + dp[n];
                float e = __expf(2.f * x);
                float th = 1.f - 2.f / (e + 1.f); // inf-safe tanh
                rs[j] += th * vv[n];
            }
        }
        #pragma unroll
        for (int off = 1; off < 16; off <<= 1) {
            #pragma unroll
            for (int j = 0; j < 4; ++j) rs[j] += __shfl_xor(rs[j], off);
        }
        if ((lane & 15) == 0) {
            size_t r = rowg + m * 16 + (lane >> 4) * 4;
            #pragma unroll
            for (int j = 0; j < 4; ++j) atomicAdd(&scores[r + j], rs[j]);
        }
    }
}

// ---------- main GEMM: ZERO BARRIERS — wave-private staging ----------
// 128^2 block tile, 4 waves (2x2 of 64x64). Each wave stages EXACTLY the
// chunks it reads (own A 64x32 + own B 64x32 = 8KB) into its own LDS region,
// double-buffered. No cross-wave dependency -> no s_barrier; each wave
// self-syncs on its OWN vmcnt (counters are per-wave). stage(h+2) issued
// after the first MFMA cluster: its lgkmcnt wait + in-order DS retirement +
// >=300cyc gload return latency make buffer-reuse races impossible.
// 64KB LDS -> 2 independent blocks/CU (8 decoupled waves, 2/SIMD).
__global__ __launch_bounds__(256, 2) void k_gemm_pw(
    const unsigned short* __restrict__ A, const unsigned short* __restrict__ Bm,
    const float* __restrict__ decp, const float* __restrict__ covp,
    const float* __restrict__ V, float* __restrict__ scores)
{
    __shared__ char lds[65536]; // 2 bufs x 4 waves x (A 4KB | B 4KB)

    int bid = blockIdx.x;
    // bijective XCD-chunked swizzle (4096 % 8 == 0): 8 n-tiles sharing an
    // A-stripe consecutive within one XCD's chunk.
    int xcd = bid & 7, local = bid >> 3;
    int T = xcd * 512 + local;
    int tile_m = T >> 3, tile_n = T & 7;
    size_t row0 = (size_t)tile_m * 128;
    int n0 = tile_n * 128;

    int t = threadIdx.x, lane = t & 63, wid = t >> 6; // 4 waves
    int wm = wid >> 1, wn = wid & 1;                  // 2x2 grid of 64x64
    int lrow = lane & 15, lk = (lane >> 4) * 8;

    // wave-private global bases: A rows wm*64.., B rows wn*64..
    const unsigned short* gA = A + (row0 + (size_t)(wm * 64) + lrow) * H_ + lk;
    const unsigned short* gB = Bm + ((size_t)(n0 + wn * 64 + lrow)) * H_ + lk;

    char* myl = lds + wid * 8192; // my region within a buffer

    f32x4 acc[4][4] = {};

    auto stage = [&](int h) {
        char* lb = myl + (h & 1) * 32768;
        #pragma unroll
        for (int c = 0; c < 4; ++c) {
            gload16(gA + (size_t)(c * 16) * H_ + h * 32, lb + c * 1024);
            gload16(gB + (size_t)(c * 16) * H_ + h * 32, lb + 4096 + c * 1024);
        }
    };

    auto body = [&](int h, bool pf) {
        const char* base = myl + (h & 1) * 32768;
        short8 af[4], bf[4];
        #pragma unroll
        for (int m = 0; m < 4; ++m) af[m] = *(const short8*)(base + m * 1024 + lane * 16);
        #pragma unroll
        for (int n = 0; n < 4; ++n) bf[n] = *(const short8*)(base + 4096 + n * 1024 + lane * 16);
        // first MFMA cluster (forces ds_reads of this buffer to retire)
        __builtin_amdgcn_s_setprio(1);
        #pragma unroll
        for (int m = 0; m < 4; ++m) {
            acc[m][0] = __builtin_amdgcn_mfma_f32_16x16x32_bf16(af[m], bf[0], acc[m][0], 0, 0, 0);
            acc[m][1] = __builtin_amdgcn_mfma_f32_16x16x32_bf16(af[m], bf[1], acc[m][1], 0, 0, 0);
        }
        __builtin_amdgcn_s_setprio(0);
        if (pf) stage(h + 2);   // safe: buffer's ds_reads retired above
        __builtin_amdgcn_s_setprio(1);
        #pragma unroll
        for (int m = 0; m < 4; ++m) {
            acc[m][2] = __builtin_amdgcn_mfma_f32_16x16x32_bf16(af[m], bf[2], acc[m][2], 0, 0, 0);
            acc[m][3] = __builtin_amdgcn_mfma_f32_16x16x32_bf16(af[m], bf[3], acc[m][3], 0, 0, 0);
        }
        __builtin_amdgcn_s_setprio(0);
    };

    // prologue: halves 0,1 in flight (16 loads, per-wave counter)
    stage(0); stage(1);

    for (int h = 0; h < 30; ++h) {
        WAITV("8");        // my half h landed; my h+1 (8 loads) still in flight
        body(h, true);     // issues my h+2 mid-body
    }
    WAITV("8"); body(30, false);
    WAITV("0"); body(31, false);

    score_epilogue(acc, n0, wm, wn, lane, row0, decp, covp, V, scores);
}

// ---------- fallback GEMM (fp32 A reg-staged, 128^2) ----------
__global__ __launch_bounds__(256, 2) void k_gemm_stage32(
    const float* __restrict__ enc, const unsigned short* __restrict__ whT,
    const float* __restrict__ decp, const float* __restrict__ covp,
    const float* __restrict__ V, float* __restrict__ scores)
{
    __shared__ uint4 lds[2][1024];
    int bid = blockIdx.x;
    int xcd = bid & 7, idx = bid >> 3;
    int tile_m = xcd * 64 + (idx >> 3);
    int tile_n = idx & 7;
    int t = threadIdx.x, lane = t & 63, wid = t >> 6;
    int wm = wid >> 1, wn = wid & 1;
    size_t row0 = (size_t)tile_m * 128;
    int n0 = tile_n * 128;
    int c0 = t, c1 = t + 256;
    int blk0 = c0 >> 6, l0 = c0 & 63, r0 = blk0 * 16 + (l0 & 15), ks0 = l0 >> 4;
    int blk1 = c1 >> 6, l1 = c1 & 63, r1 = blk1 * 16 + (l1 & 15), ks1 = l1 >> 4;
    const float* pa0 = enc + (row0 + r0) * H_ + ks0 * 8;
    const float* pa1 = enc + (row0 + r1) * H_ + ks1 * 8;
    const unsigned short* pb0 = whT + (size_t)(n0 + r0) * H_ + ks0 * 8;
    const unsigned short* pb1 = whT + (size_t)(n0 + r1) * H_ + ks1 * 8;
    f32x4 acc[4][4] = {};
    float4 a0x, a0y, a1x, a1y;
    uint4 b0, b1;
    auto LOAD = [&](int kt) {
        const float4* q0 = (const float4*)(pa0 + kt * 32);
        a0x = q0[0]; a0y = q0[1];
        const float4* q1 = (const float4*)(pa1 + kt * 32);
        a1x = q1[0]; a1y = q1[1];
        b0 = *(const uint4*)(pb0 + kt * 32);
        b1 = *(const uint4*)(pb1 + kt * 32);
    };
    auto WRITE = [&](int buf) {
        lds[buf][c0] = make_uint4(pk2(a0x.x, a0x.y), pk2(a0x.z, a0x.w),
                                  pk2(a0y.x, a0y.y), pk2(a0y.z, a0y.w));
        lds[buf][c1] = make_uint4(pk2(a1x.x, a1x.y), pk2(a1x.z, a1x.w),
                                  pk2(a1y.x, a1y.y), pk2(a1y.z, a1y.w));
        lds[buf][512 + c0] = b0;
        lds[buf][512 + c1] = b1;
    };
    LOAD(0); WRITE(0); __syncthreads();
    int cur = 0;
    for (int kt = 0; kt < 32; ++kt) {
        if (kt < 31) LOAD(kt + 1);
        const short8* LA = (const short8*)&lds[cur][0];
        const short8* LB = (const short8*)&lds[cur][512];
        short8 af[4], bf[4];
        #pragma unroll
        for (int m = 0; m < 4; ++m) af[m] = LA[(wm * 4 + m) * 64 + lane];
        #pragma unroll
        for (int n = 0; n < 4; ++n) bf[n] = LB[(wn * 4 + n) * 64 + lane];
        #pragma unroll
        for (int m = 0; m < 4; ++m)
            #pragma unroll
            for (int n = 0; n < 4; ++n)
                acc[m][n] = __builtin_amdgcn_mfma_f32_16x16x32_bf16(af[m], bf[n], acc[m][n], 0, 0, 0);
        if (kt < 31) WRITE(cur ^ 1);
        __syncthreads();
        cur ^= 1;
    }
    score_epilogue(acc, n0, wm, wn, lane, row0, decp, covp, V, scores);
}

// ---------- softmax over S per b; writes attn and coverage_new ----------
__global__ void k_softmax(const float* __restrict__ scores, const float* __restrict__ cov,
                          float* __restrict__ out) {
    int b = blockIdx.x, t = threadIdx.x;
    float* attn = out + B_ * H_;
    float* covn = out + B_ * H_ + B_ * S_;
    float v[8];
    float mx = -1e30f;
    #pragma unroll
    for (int i = 0; i < 8; ++i) {
        v[i] = scores[b * S_ + i * 256 + t];
        mx = fmaxf(mx, v[i]);
    }
    for (int off = 32; off; off >>= 1) mx = fmaxf(mx, __shfl_xor(mx, off));
    __shared__ float wsm[4], wss[4];
    if ((t & 63) == 0) wsm[t >> 6] = mx;
    __syncthreads();
    mx = fmaxf(fmaxf(wsm[0], wsm[1]), fmaxf(wsm[2], wsm[3]));
    float sum = 0.f;
    #pragma unroll
    for (int i = 0; i < 8; ++i) { v[i] = __expf(v[i] - mx); sum += v[i]; }
    for (int off = 32; off; off >>= 1) sum += __shfl_xor(sum, off);
    if ((t & 63) == 0) wss[t >> 6] = sum;
    __syncthreads();
    sum = wss[0] + wss[1] + wss[2] + wss[3];
    float inv = 1.f / sum;
    #pragma unroll
    for (int i = 0; i < 8; ++i) {
        int s = i * 256 + t;
        float a = v[i] * inv;
        attn[b * S_ + s] = a;
        covn[b * S_ + s] = cov[b * S_ + s] + a;
    }
}

// ---------- context from bf16 enc ----------
__global__ void k_context_bf(const unsigned short* __restrict__ encBF,
                             const float* __restrict__ attn, float* __restrict__ ctx) {
    int b = blockIdx.y, chunk = blockIdx.x; // 16 chunks x 128 s
    int t = threadIdx.x;
    __shared__ float sa[128];
    int s0 = chunk * 128;
    if (t < 128) sa[t] = attn[b * S_ + s0 + t];
    __syncthreads();
    float4 acc = {0.f, 0.f, 0.f, 0.f};
    const unsigned short* e = encBF + ((size_t)(b * S_ + s0)) * H_ + t * 4;
    #pragma unroll 4
    for (int s = 0; s < 128; ++s) {
        u16x4 x = *(const u16x4*)(e + (size_t)s * H_);
        float a = sa[s];
        acc.x += a * bf2f(x[0]); acc.y += a * bf2f(x[1]);
        acc.z += a * bf2f(x[2]); acc.w += a * bf2f(x[3]);
    }
    float* c = ctx + b * H_ + t * 4;
    atomicAdd(c + 0, acc.x); atomicAdd(c + 1, acc.y);
    atomicAdd(c + 2, acc.z); atomicAdd(c + 3, acc.w);
}

// ---------- context from fp32 enc (fallback) ----------
__global__ void k_context_f32(const float* __restrict__ enc, const float* __restrict__ attn,
                              float* __restrict__ ctx) {
    int b = blockIdx.y, chunk = blockIdx.x;
    int t = threadIdx.x;
    __shared__ float sa[128];
    int s0 = chunk * 128;
    if (t < 128) sa[t] = attn[b * S_ + s0 + t];
    __syncthreads();
    float4 acc = {0.f, 0.f, 0.f, 0.f};
    const float4* e = (const float4*)(enc + ((size_t)b * S_ + s0) * H_) + t;
    #pragma unroll 4
    for (int s = 0; s < 128; ++s) {
        float4 x = e[(size_t)s * (H_ / 4)];
        float a = sa[s];
        acc.x += a * x.x; acc.y += a * x.y; acc.z += a * x.z; acc.w += a * x.w;
    }
    float* c = ctx + b * H_ + t * 4;
    atomicAdd(c + 0, acc.x); atomicAdd(c + 1, acc.y);
    atomicAdd(c + 2, acc.z); atomicAdd(c + 3, acc.w);
}

extern "C" void kernel_launch(void* const* d_in, const int* in_sizes, int n_in,
                              void* d_out, int out_size, void* d_ws, size_t ws_size,
                              hipStream_t stream) {
    (void)in_sizes; (void)n_in; (void)out_size;
    const float* ds  = (const float*)d_in[0];
    const float* enc = (const float*)d_in[1];
    const float* cov = (const float*)d_in[2];
    const float* Wh  = (const float*)d_in[3];
    const float* bh  = (const float*)d_in[4];
    const float* Ws  = (const float*)d_in[5];
    const float* bs  = (const float*)d_in[6];
    const float* V   = (const float*)d_in[7];
    // d_in[8] = bv: softmax-invariant constant -> unused
    const float* Wc  = (const float*)d_in[9];
    const float* bc  = (const float*)d_in[10];
    float* out = (float*)d_out;

    float* ws_scores = (float*)d_ws;                          // 65536 f32
    float* ws_decp   = ws_scores + B_ * S_;                   // 32768 f32
    float* ws_covp   = ws_decp + B_ * H_;                     // 64 f32
    unsigned short* ws_whT = (unsigned short*)(ws_covp + 64); // 1M bf16 (2MB)
    unsigned short* ws_encBF = ws_whT + (size_t)H_ * H_;      // 64M bf16 (128MB)
    const size_t need_full = ((char*)(ws_encBF + (size_t)B_ * S_ * H_)) - (char*)d_ws;

    hipMemsetAsync(ws_scores, 0, B_ * S_ * sizeof(float), stream);
    hipMemsetAsync(out, 0, B_ * H_ * sizeof(float), stream); // context accumulators

    k_whT<<<dim3(16, 16), dim3(64, 4), 0, stream>>>(Wh, ws_whT);
    k_decp2<<<dim3(4, 16), 256, 0, stream>>>(ds, Ws, bs, bh, ws_decp);
    k_covp<<<32, 256, 0, stream>>>(cov, Wc, bc, ws_covp);

    if (ws_size >= need_full) {
        k_cvt<<<2048, 256, 0, stream>>>(enc, (uint4*)ws_encBF, (B_ * S_ * H_) / 8);
        k_gemm_pw<<<4096, 256, 0, stream>>>(ws_encBF, ws_whT, ws_decp, ws_covp, V, ws_scores);
        k_softmax<<<32, 256, 0, stream>>>(ws_scores, cov, out);
        k_context_bf<<<dim3(16, 32), 256, 0, stream>>>(ws_encBF, out + B_ * H_, out);
    } else {
        k_gemm_stage32<<<4096, 256, 0, stream>>>(enc, ws_whT, ws_decp, ws_covp, V, ws_scores);
        k_softmax<<<32, 256, 0, stream>>>(ws_scores, cov, out);
        k_context_f32<<<dim3(16, 32), 256, 0, stream>>>(enc, out + B_ * H_, out);
    }
}

// Round 11
// 413.650 us; speedup vs baseline: 1.7005x; 1.7005x over previous
//
#include <hip/hip_runtime.h>

#define B_ 32
#define S_ 2048
#define H_ 1024

typedef __attribute__((ext_vector_type(8))) short short8;
typedef __attribute__((ext_vector_type(4))) float f32x4;
typedef __attribute__((ext_vector_type(4))) unsigned short u16x4;

__device__ __forceinline__ unsigned short f2bf(float f) {
    unsigned u = __builtin_bit_cast(unsigned, f);
    u += 0x7FFFu + ((u >> 16) & 1u);
    return (unsigned short)(u >> 16);
}
__device__ __forceinline__ unsigned pk2(float x, float y) {
    return (unsigned)f2bf(x) | ((unsigned)f2bf(y) << 16);
}
__device__ __forceinline__ float bf2f(unsigned short u) {
    unsigned x = ((unsigned)u) << 16;
    return __builtin_bit_cast(float, x);
}
__device__ __forceinline__ void gload16(const void* g, void* l) {
    __builtin_amdgcn_global_load_lds((const __attribute__((address_space(1))) void*)g,
                                     (__attribute__((address_space(3))) void*)l, 16, 0, 0);
}

#define WAITV(nstr) asm volatile("s_waitcnt vmcnt(" nstr ")" ::: "memory")

// ---------- enc fp32 -> bf16 ----------
__global__ void k_cvt(const float* __restrict__ in, uint4* __restrict__ out, int ngroups) {
    int i = blockIdx.x * blockDim.x + threadIdx.x;
    int stride = gridDim.x * blockDim.x;
    for (; i < ngroups; i += stride) {
        const float4* p = (const float4*)in + (size_t)i * 2;
        float4 x = p[0], y = p[1];
        out[i] = make_uint4(pk2(x.x, x.y), pk2(x.z, x.w), pk2(y.x, y.y), pk2(y.z, y.w));
    }
}

// ---------- prep: Wh (K,N) fp32 -> WhT (N,K) bf16 ----------
__global__ void k_whT(const float* __restrict__ Wh, unsigned short* __restrict__ whT) {
    __shared__ float tile[64][65];
    int k0 = blockIdx.x * 64, n0 = blockIdx.y * 64;
    int tx = threadIdx.x, ty = threadIdx.y; // (64,4)
    #pragma unroll
    for (int i = 0; i < 16; ++i) {
        int r = ty + i * 4;
        tile[r][tx] = Wh[(size_t)(k0 + r) * H_ + n0 + tx];
    }
    __syncthreads();
    #pragma unroll
    for (int i = 0; i < 16; ++i) {
        int r = ty + i * 4;
        whT[(size_t)(n0 + r) * H_ + k0 + tx] = f2bf(tile[tx][r]);
    }
}

// ---------- prep: decp for 2 batches/block (halves Ws traffic) ----------
__global__ void k_decp2(const float* __restrict__ ds, const float* __restrict__ Ws,
                        const float* __restrict__ bs, const float* __restrict__ bh,
                        float* __restrict__ decp) {
    __shared__ float sd[2][1024];
    int tid = threadIdx.x;
    int n = blockIdx.x * 256 + tid;
    int b0 = blockIdx.y * 2;
    for (int i = tid; i < 2048; i += 256) sd[i >> 10][i & 1023] = ds[b0 * H_ + i];
    __syncthreads();
    float a0 = 0.f, a1 = 0.f;
    #pragma unroll 4
    for (int k = 0; k < H_; ++k) {
        float w = Ws[(size_t)k * H_ + n];
        a0 += sd[0][k] * w;
        a1 += sd[1][k] * w;
    }
    float bias = bs[n] + bh[n];
    decp[(b0 + 0) * H_ + n] = a0 + bias;
    decp[(b0 + 1) * H_ + n] = a1 + bias;
}

// ---------- prep: covp[b] = cov[b]@Wc + bc ----------
__global__ void k_covp(const float* __restrict__ cov, const float* __restrict__ Wc,
                       const float* __restrict__ bc, float* __restrict__ covp) {
    int b = blockIdx.x, t = threadIdx.x;
    float p = 0.f;
    for (int s = t; s < S_; s += 256) p += cov[b * S_ + s] * Wc[s];
    for (int off = 32; off; off >>= 1) p += __shfl_down(p, off);
    __shared__ float w[4];
    if ((t & 63) == 0) w[t >> 6] = p;
    __syncthreads();
    if (t == 0) covp[b] = w[0] + w[1] + w[2] + w[3] + bc[0];
}

// ---------- main GEMM: 256x256 tile, 8 waves, BK=64, 8-phase counted-vmcnt ----------
// Best measured structure (rounds 3/4: 205us, 670 TF). LDS: 4 half-buffers x
// 32KB; chunk (1KB) = 16 rows x 32 k lane-linear. 4 phases per half-tile,
// each {ds_reads | gload issue | barrier | setprio MFMA | barrier}; counted
// vmcnt(8) twice per K-tile, drains only at tail.
__global__ __launch_bounds__(512, 2) void k_gemm_8p(
    const unsigned short* __restrict__ A, const unsigned short* __restrict__ Bm,
    const float* __restrict__ decp, const float* __restrict__ covp,
    const float* __restrict__ V, float* __restrict__ scores)
{
    __shared__ char lds[131072];

    int bid = blockIdx.x;
    int xcd = bid & 7, local = bid >> 3;
    int T = xcd * 128 + local;
    int tile_m = T >> 2, tile_n = T & 3;
    size_t row0 = (size_t)tile_m * 256;
    int n0 = tile_n * 256;

    int t = threadIdx.x, lane = t & 63, wid = t >> 6; // 8 waves
    int wm = wid >> 2, wn = wid & 3;                  // 2 x 4 wave grid
    int lrow = lane & 15, lk = (lane >> 4) * 8;

    const unsigned short* gA0 = A + (row0 + (size_t)(wid * 32) + lrow) * H_ + lk;
    const unsigned short* gA1 = gA0 + (size_t)16 * H_;
    const unsigned short* gB0 = Bm + ((size_t)(n0 + wid * 32 + lrow)) * H_ + lk;
    const unsigned short* gB1 = gB0 + (size_t)16 * H_;

    f32x4 acc[8][4] = {};
    short8 bfr[4];

    auto stA = [&](int h) {
        char* lb = lds + (h & 3) * 32768;
        gload16(gA0 + h * 32, lb + (2 * wid) * 1024);
        gload16(gA1 + h * 32, lb + (2 * wid + 1) * 1024);
    };
    auto stB = [&](int h) {
        char* lb = lds + (h & 3) * 32768 + 16384;
        gload16(gB0 + h * 32, lb + (2 * wid) * 1024);
        gload16(gB1 + h * 32, lb + (2 * wid + 1) * 1024);
    };

#define PHASE(h, MH, ISSUE) do { \
    const char* hb_ = lds + ((h) & 3) * 32768; \
    short8 af_[4]; \
    af_[0] = *(const short8*)(hb_ + (wm * 8 + (MH)*4 + 0) * 1024 + lane * 16); \
    af_[1] = *(const short8*)(hb_ + (wm * 8 + (MH)*4 + 1) * 1024 + lane * 16); \
    af_[2] = *(const short8*)(hb_ + (wm * 8 + (MH)*4 + 2) * 1024 + lane * 16); \
    af_[3] = *(const short8*)(hb_ + (wm * 8 + (MH)*4 + 3) * 1024 + lane * 16); \
    if ((MH) == 0) { \
        bfr[0] = *(const short8*)(hb_ + 16384 + (wn * 4 + 0) * 1024 + lane * 16); \
        bfr[1] = *(const short8*)(hb_ + 16384 + (wn * 4 + 1) * 1024 + lane * 16); \
        bfr[2] = *(const short8*)(hb_ + 16384 + (wn * 4 + 2) * 1024 + lane * 16); \
        bfr[3] = *(const short8*)(hb_ + 16384 + (wn * 4 + 3) * 1024 + lane * 16); \
    } \
    ISSUE; \
    __builtin_amdgcn_s_barrier(); \
    __builtin_amdgcn_s_setprio(1); \
    _Pragma("unroll") \
    for (int i_ = 0; i_ < 4; ++i_) { \
        acc[(MH)*4 + i_][0] = __builtin_amdgcn_mfma_f32_16x16x32_bf16(af_[i_], bfr[0], acc[(MH)*4 + i_][0], 0, 0, 0); \
        acc[(MH)*4 + i_][1] = __builtin_amdgcn_mfma_f32_16x16x32_bf16(af_[i_], bfr[1], acc[(MH)*4 + i_][1], 0, 0, 0); \
        acc[(MH)*4 + i_][2] = __builtin_amdgcn_mfma_f32_16x16x32_bf16(af_[i_], bfr[2], acc[(MH)*4 + i_][2], 0, 0, 0); \
        acc[(MH)*4 + i_][3] = __builtin_amdgcn_mfma_f32_16x16x32_bf16(af_[i_], bfr[3], acc[(MH)*4 + i_][3], 0, 0, 0); \
    } \
    __builtin_amdgcn_s_setprio(0); \
    __builtin_amdgcn_s_barrier(); \
} while (0)

    stA(0); stB(0); stA(1); stB(1); stA(2); stB(2);

    for (int tt = 0; tt < 14; ++tt) {
        int h0 = 2 * tt, h1 = 2 * tt + 1;
        WAITV("8"); __builtin_amdgcn_s_barrier();
        PHASE(h0, 0, stA(h1 + 2));
        PHASE(h0, 1, stB(h1 + 2));
        WAITV("8"); __builtin_amdgcn_s_barrier();
        PHASE(h1, 0, stA(h1 + 3));
        PHASE(h1, 1, stB(h1 + 3));
    }
    WAITV("8"); __builtin_amdgcn_s_barrier();
    PHASE(28, 0, stA(31));
    PHASE(28, 1, stB(31));
    WAITV("8"); __builtin_amdgcn_s_barrier();
    PHASE(29, 0, (void)0);
    PHASE(29, 1, (void)0);
    WAITV("4"); __builtin_amdgcn_s_barrier();
    PHASE(30, 0, (void)0);
    PHASE(30, 1, (void)0);
    WAITV("0"); __builtin_amdgcn_s_barrier();
    PHASE(31, 0, (void)0);
    PHASE(31, 1, (void)0);
#undef PHASE

    // ---- epilogue: tanh + V-dot + 16-lane reduce + atomicAdd ----
    int colb = n0 + wn * 64 + (lane & 15);
    size_t rowg = row0 + (size_t)wm * 128;
    int b = (int)(row0 >> 11);
    float cb = covp[b];
    float vv[4], dp[4];
    #pragma unroll
    for (int n = 0; n < 4; ++n) {
        int c = colb + n * 16;
        vv[n] = V[c];
        dp[n] = decp[b * H_ + c] + cb;
    }
    #pragma unroll
    for (int m = 0; m < 8; ++m) {
        float rs[4] = {0.f, 0.f, 0.f, 0.f};
        #pragma unroll
        for (int n = 0; n < 4; ++n) {
            f32x4 Aq = acc[m][n];
            #pragma unroll
            for (int j = 0; j < 4; ++j) {
                float x = Aq[j] + dp[n];
                float e = __expf(2.f * x);
                float th = 1.f - 2.f / (e + 1.f); // inf-safe tanh
                rs[j] += th * vv[n];
            }
        }
        #pragma unroll
        for (int off = 1; off < 16; off <<= 1) {
            #pragma unroll
            for (int j = 0; j < 4; ++j) rs[j] += __shfl_xor(rs[j], off);
        }
        if ((lane & 15) == 0) {
            size_t r = rowg + m * 16 + (lane >> 4) * 4;
            #pragma unroll
            for (int j = 0; j < 4; ++j) atomicAdd(&scores[r + j], rs[j]);
        }
    }
}

// ---------- fallback epilogue (4-wave kernel) ----------
__device__ __forceinline__ void score_epilogue(
    f32x4 acc[4][4], int n0, int wm, int wn, int lane, size_t row0,
    const float* __restrict__ decp, const float* __restrict__ covp,
    const float* __restrict__ V, float* __restrict__ scores)
{
    int colb = n0 + wn * 64 + (lane & 15);
    size_t rowg = row0 + (size_t)wm * 64;
    int b = (int)(rowg >> 11);
    float cb = covp[b];
    float vv[4], dp[4];
    #pragma unroll
    for (int n = 0; n < 4; ++n) {
        int c = colb + n * 16;
        vv[n] = V[c];
        dp[n] = decp[b * H_ + c] + cb;
    }
    #pragma unroll
    for (int m = 0; m < 4; ++m) {
        float rs[4] = {0.f, 0.f, 0.f, 0.f};
        #pragma unroll
        for (int n = 0; n < 4; ++n) {
            f32x4 A = acc[m][n];
            #pragma unroll
            for (int j = 0; j < 4; ++j) {
                float x = A[j] + dp[n];
                float e = __expf(2.f * x);
                float th = 1.f - 2.f / (e + 1.f);
                rs[j] += th * vv[n];
            }
        }
        #pragma unroll
        for (int off = 1; off < 16; off <<= 1) {
            #pragma unroll
            for (int j = 0; j < 4; ++j) rs[j] += __shfl_xor(rs[j], off);
        }
        if ((lane & 15) == 0) {
            size_t r = rowg + m * 16 + (lane >> 4) * 4;
            #pragma unroll
            for (int j = 0; j < 4; ++j) atomicAdd(&scores[r + j], rs[j]);
        }
    }
}

// ---------- fallback GEMM (fp32 A reg-staged, 128^2) ----------
__global__ __launch_bounds__(256, 2) void k_gemm_stage32(
    const float* __restrict__ enc, const unsigned short* __restrict__ whT,
    const float* __restrict__ decp, const float* __restrict__ covp,
    const float* __restrict__ V, float* __restrict__ scores)
{
    __shared__ uint4 lds[2][1024];
    int bid = blockIdx.x;
    int xcd = bid & 7, idx = bid >> 3;
    int tile_m = xcd * 64 + (idx >> 3);
    int tile_n = idx & 7;
    int t = threadIdx.x, lane = t & 63, wid = t >> 6;
    int wm = wid >> 1, wn = wid & 1;
    size_t row0 = (size_t)tile_m * 128;
    int n0 = tile_n * 128;
    int c0 = t, c1 = t + 256;
    int blk0 = c0 >> 6, l0 = c0 & 63, r0 = blk0 * 16 + (l0 & 15), ks0 = l0 >> 4;
    int blk1 = c1 >> 6, l1 = c1 & 63, r1 = blk1 * 16 + (l1 & 15), ks1 = l1 >> 4;
    const float* pa0 = enc + (row0 + r0) * H_ + ks0 * 8;
    const float* pa1 = enc + (row0 + r1) * H_ + ks1 * 8;
    const unsigned short* pb0 = whT + (size_t)(n0 + r0) * H_ + ks0 * 8;
    const unsigned short* pb1 = whT + (size_t)(n0 + r1) * H_ + ks1 * 8;
    f32x4 acc[4][4] = {};
    float4 a0x, a0y, a1x, a1y;
    uint4 b0, b1;
    auto LOAD = [&](int kt) {
        const float4* q0 = (const float4*)(pa0 + kt * 32);
        a0x = q0[0]; a0y = q0[1];
        const float4* q1 = (const float4*)(pa1 + kt * 32);
        a1x = q1[0]; a1y = q1[1];
        b0 = *(const uint4*)(pb0 + kt * 32);
        b1 = *(const uint4*)(pb1 + kt * 32);
    };
    auto WRITE = [&](int buf) {
        lds[buf][c0] = make_uint4(pk2(a0x.x, a0x.y), pk2(a0x.z, a0x.w),
                                  pk2(a0y.x, a0y.y), pk2(a0y.z, a0y.w));
        lds[buf][c1] = make_uint4(pk2(a1x.x, a1x.y), pk2(a1x.z, a1x.w),
                                  pk2(a1y.x, a1y.y), pk2(a1y.z, a1y.w));
        lds[buf][512 + c0] = b0;
        lds[buf][512 + c1] = b1;
    };
    LOAD(0); WRITE(0); __syncthreads();
    int cur = 0;
    for (int kt = 0; kt < 32; ++kt) {
        if (kt < 31) LOAD(kt + 1);
        const short8* LA = (const short8*)&lds[cur][0];
        const short8* LB = (const short8*)&lds[cur][512];
        short8 af[4], bf[4];
        #pragma unroll
        for (int m = 0; m < 4; ++m) af[m] = LA[(wm * 4 + m) * 64 + lane];
        #pragma unroll
        for (int n = 0; n < 4; ++n) bf[n] = LB[(wn * 4 + n) * 64 + lane];
        #pragma unroll
        for (int m = 0; m < 4; ++m)
            #pragma unroll
            for (int n = 0; n < 4; ++n)
                acc[m][n] = __builtin_amdgcn_mfma_f32_16x16x32_bf16(af[m], bf[n], acc[m][n], 0, 0, 0);
        if (kt < 31) WRITE(cur ^ 1);
        __syncthreads();
        cur ^= 1;
    }
    score_epilogue(acc, n0, wm, wn, lane, row0, decp, covp, V, scores);
}

// ---------- softmax over S per b; writes attn and coverage_new ----------
__global__ void k_softmax(const float* __restrict__ scores, const float* __restrict__ cov,
                          float* __restrict__ out) {
    int b = blockIdx.x, t = threadIdx.x;
    float* attn = out + B_ * H_;
    float* covn = out + B_ * H_ + B_ * S_;
    float v[8];
    float mx = -1e30f;
    #pragma unroll
    for (int i = 0; i < 8; ++i) {
        v[i] = scores[b * S_ + i * 256 + t];
        mx = fmaxf(mx, v[i]);
    }
    for (int off = 32; off; off >>= 1) mx = fmaxf(mx, __shfl_xor(mx, off));
    __shared__ float wsm[4], wss[4];
    if ((t & 63) == 0) wsm[t >> 6] = mx;
    __syncthreads();
    mx = fmaxf(fmaxf(wsm[0], wsm[1]), fmaxf(wsm[2], wsm[3]));
    float sum = 0.f;
    #pragma unroll
    for (int i = 0; i < 8; ++i) { v[i] = __expf(v[i] - mx); sum += v[i]; }
    for (int off = 32; off; off >>= 1) sum += __shfl_xor(sum, off);
    if ((t & 63) == 0) wss[t >> 6] = sum;
    __syncthreads();
    sum = wss[0] + wss[1] + wss[2] + wss[3];
    float inv = 1.f / sum;
    #pragma unroll
    for (int i = 0; i < 8; ++i) {
        int s = i * 256 + t;
        float a = v[i] * inv;
        attn[b * S_ + s] = a;
        covn[b * S_ + s] = cov[b * S_ + s] + a;
    }
}

// ---------- context from bf16 enc ----------
__global__ void k_context_bf(const unsigned short* __restrict__ encBF,
                             const float* __restrict__ attn, float* __restrict__ ctx) {
    int b = blockIdx.y, chunk = blockIdx.x; // 16 chunks x 128 s
    int t = threadIdx.x;
    __shared__ float sa[128];
    int s0 = chunk * 128;
    if (t < 128) sa[t] = attn[b * S_ + s0 + t];
    __syncthreads();
    float4 acc = {0.f, 0.f, 0.f, 0.f};
    const unsigned short* e = encBF + ((size_t)(b * S_ + s0)) * H_ + t * 4;
    #pragma unroll 4
    for (int s = 0; s < 128; ++s) {
        u16x4 x = *(const u16x4*)(e + (size_t)s * H_);
        float a = sa[s];
        acc.x += a * bf2f(x[0]); acc.y += a * bf2f(x[1]);
        acc.z += a * bf2f(x[2]); acc.w += a * bf2f(x[3]);
    }
    float* c = ctx + b * H_ + t * 4;
    atomicAdd(c + 0, acc.x); atomicAdd(c + 1, acc.y);
    atomicAdd(c + 2, acc.z); atomicAdd(c + 3, acc.w);
}

// ---------- context from fp32 enc (fallback) ----------
__global__ void k_context_f32(const float* __restrict__ enc, const float* __restrict__ attn,
                              float* __restrict__ ctx) {
    int b = blockIdx.y, chunk = blockIdx.x;
    int t = threadIdx.x;
    __shared__ float sa[128];
    int s0 = chunk * 128;
    if (t < 128) sa[t] = attn[b * S_ + s0 + t];
    __syncthreads();
    float4 acc = {0.f, 0.f, 0.f, 0.f};
    const float4* e = (const float4*)(enc + ((size_t)b * S_ + s0) * H_) + t;
    #pragma unroll 4
    for (int s = 0; s < 128; ++s) {
        float4 x = e[(size_t)s * (H_ / 4)];
        float a = sa[s];
        acc.x += a * x.x; acc.y += a * x.y; acc.z += a * x.z; acc.w += a * x.w;
    }
    float* c = ctx + b * H_ + t * 4;
    atomicAdd(c + 0, acc.x); atomicAdd(c + 1, acc.y);
    atomicAdd(c + 2, acc.z); atomicAdd(c + 3, acc.w);
}

extern "C" void kernel_launch(void* const* d_in, const int* in_sizes, int n_in,
                              void* d_out, int out_size, void* d_ws, size_t ws_size,
                              hipStream_t stream) {
    (void)in_sizes; (void)n_in; (void)out_size;
    const float* ds  = (const float*)d_in[0];
    const float* enc = (const float*)d_in[1];
    const float* cov = (const float*)d_in[2];
    const float* Wh  = (const float*)d_in[3];
    const float* bh  = (const float*)d_in[4];
    const float* Ws  = (const float*)d_in[5];
    const float* bs  = (const float*)d_in[6];
    const float* V   = (const float*)d_in[7];
    // d_in[8] = bv: softmax-invariant constant -> unused
    const float* Wc  = (const float*)d_in[9];
    const float* bc  = (const float*)d_in[10];
    float* out = (float*)d_out;

    float* ws_scores = (float*)d_ws;                          // 65536 f32
    float* ws_decp   = ws_scores + B_ * S_;                   // 32768 f32
    float* ws_covp   = ws_decp + B_ * H_;                     // 64 f32
    unsigned short* ws_whT = (unsigned short*)(ws_covp + 64); // 1M bf16 (2MB)
    unsigned short* ws_encBF = ws_whT + (size_t)H_ * H_;      // 64M bf16 (128MB)
    const size_t need_full = ((char*)(ws_encBF + (size_t)B_ * S_ * H_)) - (char*)d_ws;

    hipMemsetAsync(ws_scores, 0, B_ * S_ * sizeof(float), stream);
    hipMemsetAsync(out, 0, B_ * H_ * sizeof(float), stream); // context accumulators

    k_whT<<<dim3(16, 16), dim3(64, 4), 0, stream>>>(Wh, ws_whT);
    k_decp2<<<dim3(4, 16), 256, 0, stream>>>(ds, Ws, bs, bh, ws_decp);
    k_covp<<<32, 256, 0, stream>>>(cov, Wc, bc, ws_covp);

    if (ws_size >= need_full) {
        k_cvt<<<2048, 256, 0, stream>>>(enc, (uint4*)ws_encBF, (B_ * S_ * H_) / 8);
        k_gemm_8p<<<1024, 512, 0, stream>>>(ws_encBF, ws_whT, ws_decp, ws_covp, V, ws_scores);
        k_softmax<<<32, 256, 0, stream>>>(ws_scores, cov, out);
        k_context_bf<<<dim3(16, 32), 256, 0, stream>>>(ws_encBF, out + B_ * H_, out);
    } else {
        k_gemm_stage32<<<4096, 256, 0, stream>>>(enc, ws_whT, ws_decp, ws_covp, V, ws_scores);
        k_softmax<<<32, 256, 0, stream>>>(ws_scores, cov, out);
        k_context_f32<<<dim3(16, 32), 256, 0, stream>>>(enc, out + B_ * H_, out);
    }
}

// Round 12
// 313.355 us; speedup vs baseline: 2.2448x; 1.3201x over previous
//
#include <hip/hip_runtime.h>

#define B_ 32
#define S_ 2048
#define H_ 1024

typedef __attribute__((ext_vector_type(8))) short short8;
typedef __attribute__((ext_vector_type(4))) float f32x4;
typedef __attribute__((ext_vector_type(4))) unsigned short u16x4;

__device__ __forceinline__ unsigned short f2bf(float f) {
    unsigned u = __builtin_bit_cast(unsigned, f);
    u += 0x7FFFu + ((u >> 16) & 1u);
    return (unsigned short)(u >> 16);
}
__device__ __forceinline__ unsigned pk2(float x, float y) {
    return (unsigned)f2bf(x) | ((unsigned)f2bf(y) << 16);
}
__device__ __forceinline__ float bf2f(unsigned short u) {
    unsigned x = ((unsigned)u) << 16;
    return __builtin_bit_cast(float, x);
}
__device__ __forceinline__ void gload16(const void* g, void* l) {
    __builtin_amdgcn_global_load_lds((const __attribute__((address_space(1))) void*)g,
                                     (__attribute__((address_space(3))) void*)l, 16, 0, 0);
}

#define WAITV(nstr) asm volatile("s_waitcnt vmcnt(" nstr ")" ::: "memory")

// ---------- enc fp32 -> bf16 ----------
__global__ void k_cvt(const float* __restrict__ in, uint4* __restrict__ out, int ngroups) {
    int i = blockIdx.x * blockDim.x + threadIdx.x;
    int stride = gridDim.x * blockDim.x;
    for (; i < ngroups; i += stride) {
        const float4* p = (const float4*)in + (size_t)i * 2;
        float4 x = p[0], y = p[1];
        out[i] = make_uint4(pk2(x.x, x.y), pk2(x.z, x.w), pk2(y.x, y.y), pk2(y.z, y.w));
    }
}

// ---------- prep: Wh (K,N) fp32 -> WhT (N,K) bf16 ----------
__global__ void k_whT(const float* __restrict__ Wh, unsigned short* __restrict__ whT) {
    __shared__ float tile[64][65];
    int k0 = blockIdx.x * 64, n0 = blockIdx.y * 64;
    int tx = threadIdx.x, ty = threadIdx.y; // (64,4)
    #pragma unroll
    for (int i = 0; i < 16; ++i) {
        int r = ty + i * 4;
        tile[r][tx] = Wh[(size_t)(k0 + r) * H_ + n0 + tx];
    }
    __syncthreads();
    #pragma unroll
    for (int i = 0; i < 16; ++i) {
        int r = ty + i * 4;
        whT[(size_t)(n0 + r) * H_ + k0 + tx] = f2bf(tile[tx][r]);
    }
}

// ---------- prep: decp[b][n] = ds[b]@Ws[:,n] + bs[n] + bh[n], split-K x4 ----------
// 512 blocks (8 waves/CU) instead of 128: the k-chain is 256-deep per block and
// Ws panels stream at full BW. Partials atomicAdd into zero-init'd decp; the
// kz==0 block contributes the bias.
__global__ void k_decp_sk(const float* __restrict__ ds, const float* __restrict__ Ws,
                          const float* __restrict__ bs, const float* __restrict__ bh,
                          float* __restrict__ decp) {
    int n = blockIdx.x * 256 + threadIdx.x;
    int b = blockIdx.y;
    int k0 = blockIdx.z * 256;
    float a0 = 0.f, a1 = 0.f, a2 = 0.f, a3 = 0.f;
    for (int k = k0; k < k0 + 256; k += 4) {
        a0 += ds[b * H_ + k + 0] * Ws[(size_t)(k + 0) * H_ + n];
        a1 += ds[b * H_ + k + 1] * Ws[(size_t)(k + 1) * H_ + n];
        a2 += ds[b * H_ + k + 2] * Ws[(size_t)(k + 2) * H_ + n];
        a3 += ds[b * H_ + k + 3] * Ws[(size_t)(k + 3) * H_ + n];
    }
    float a = a0 + a1 + a2 + a3;
    if (blockIdx.z == 0) a += bs[n] + bh[n];
    atomicAdd(&decp[b * H_ + n], a);
}

// ---------- prep: covp[b] = cov[b]@Wc + bc ----------
__global__ void k_covp(const float* __restrict__ cov, const float* __restrict__ Wc,
                       const float* __restrict__ bc, float* __restrict__ covp) {
    int b = blockIdx.x, t = threadIdx.x;
    float p = 0.f;
    for (int s = t; s < S_; s += 256) p += cov[b * S_ + s] * Wc[s];
    for (int off = 32; off; off >>= 1) p += __shfl_down(p, off);
    __shared__ float w[4];
    if ((t & 63) == 0) w[t >> 6] = p;
    __syncthreads();
    if (t == 0) covp[b] = w[0] + w[1] + w[2] + w[3] + bc[0];
}

// ---------- main GEMM: 256x256 tile, 8 waves, BK=64, 8-phase counted-vmcnt ----------
// Best measured structure (205us, ~670 TF). LDS: 4 half-buffers x 32KB; chunk
// (1KB) = 16 rows x 32 k lane-linear. 4 phases per half-tile; counted vmcnt(8)
// twice per K-tile; drains only at tail.
__global__ __launch_bounds__(512, 2) void k_gemm_8p(
    const unsigned short* __restrict__ A, const unsigned short* __restrict__ Bm,
    const float* __restrict__ decp, const float* __restrict__ covp,
    const float* __restrict__ V, float* __restrict__ scores)
{
    __shared__ char lds[131072];

    int bid = blockIdx.x;
    int xcd = bid & 7, local = bid >> 3;
    int T = xcd * 128 + local;
    int tile_m = T >> 2, tile_n = T & 3;
    size_t row0 = (size_t)tile_m * 256;
    int n0 = tile_n * 256;

    int t = threadIdx.x, lane = t & 63, wid = t >> 6; // 8 waves
    int wm = wid >> 2, wn = wid & 3;                  // 2 x 4 wave grid
    int lrow = lane & 15, lk = (lane >> 4) * 8;

    const unsigned short* gA0 = A + (row0 + (size_t)(wid * 32) + lrow) * H_ + lk;
    const unsigned short* gA1 = gA0 + (size_t)16 * H_;
    const unsigned short* gB0 = Bm + ((size_t)(n0 + wid * 32 + lrow)) * H_ + lk;
    const unsigned short* gB1 = gB0 + (size_t)16 * H_;

    f32x4 acc[8][4] = {};
    short8 bfr[4];

    auto stA = [&](int h) {
        char* lb = lds + (h & 3) * 32768;
        gload16(gA0 + h * 32, lb + (2 * wid) * 1024);
        gload16(gA1 + h * 32, lb + (2 * wid + 1) * 1024);
    };
    auto stB = [&](int h) {
        char* lb = lds + (h & 3) * 32768 + 16384;
        gload16(gB0 + h * 32, lb + (2 * wid) * 1024);
        gload16(gB1 + h * 32, lb + (2 * wid + 1) * 1024);
    };

#define PHASE(h, MH, ISSUE) do { \
    const char* hb_ = lds + ((h) & 3) * 32768; \
    short8 af_[4]; \
    af_[0] = *(const short8*)(hb_ + (wm * 8 + (MH)*4 + 0) * 1024 + lane * 16); \
    af_[1] = *(const short8*)(hb_ + (wm * 8 + (MH)*4 + 1) * 1024 + lane * 16); \
    af_[2] = *(const short8*)(hb_ + (wm * 8 + (MH)*4 + 2) * 1024 + lane * 16); \
    af_[3] = *(const short8*)(hb_ + (wm * 8 + (MH)*4 + 3) * 1024 + lane * 16); \
    if ((MH) == 0) { \
        bfr[0] = *(const short8*)(hb_ + 16384 + (wn * 4 + 0) * 1024 + lane * 16); \
        bfr[1] = *(const short8*)(hb_ + 16384 + (wn * 4 + 1) * 1024 + lane * 16); \
        bfr[2] = *(const short8*)(hb_ + 16384 + (wn * 4 + 2) * 1024 + lane * 16); \
        bfr[3] = *(const short8*)(hb_ + 16384 + (wn * 4 + 3) * 1024 + lane * 16); \
    } \
    ISSUE; \
    __builtin_amdgcn_s_barrier(); \
    __builtin_amdgcn_s_setprio(1); \
    _Pragma("unroll") \
    for (int i_ = 0; i_ < 4; ++i_) { \
        acc[(MH)*4 + i_][0] = __builtin_amdgcn_mfma_f32_16x16x32_bf16(af_[i_], bfr[0], acc[(MH)*4 + i_][0], 0, 0, 0); \
        acc[(MH)*4 + i_][1] = __builtin_amdgcn_mfma_f32_16x16x32_bf16(af_[i_], bfr[1], acc[(MH)*4 + i_][1], 0, 0, 0); \
        acc[(MH)*4 + i_][2] = __builtin_amdgcn_mfma_f32_16x16x32_bf16(af_[i_], bfr[2], acc[(MH)*4 + i_][2], 0, 0, 0); \
        acc[(MH)*4 + i_][3] = __builtin_amdgcn_mfma_f32_16x16x32_bf16(af_[i_], bfr[3], acc[(MH)*4 + i_][3], 0, 0, 0); \
    } \
    __builtin_amdgcn_s_setprio(0); \
    __builtin_amdgcn_s_barrier(); \
} while (0)

    stA(0); stB(0); stA(1); stB(1); stA(2); stB(2);

    for (int tt = 0; tt < 14; ++tt) {
        int h0 = 2 * tt, h1 = 2 * tt + 1;
        WAITV("8"); __builtin_amdgcn_s_barrier();
        PHASE(h0, 0, stA(h1 + 2));
        PHASE(h0, 1, stB(h1 + 2));
        WAITV("8"); __builtin_amdgcn_s_barrier();
        PHASE(h1, 0, stA(h1 + 3));
        PHASE(h1, 1, stB(h1 + 3));
    }
    WAITV("8"); __builtin_amdgcn_s_barrier();
    PHASE(28, 0, stA(31));
    PHASE(28, 1, stB(31));
    WAITV("8"); __builtin_amdgcn_s_barrier();
    PHASE(29, 0, (void)0);
    PHASE(29, 1, (void)0);
    WAITV("4"); __builtin_amdgcn_s_barrier();
    PHASE(30, 0, (void)0);
    PHASE(30, 1, (void)0);
    WAITV("0"); __builtin_amdgcn_s_barrier();
    PHASE(31, 0, (void)0);
    PHASE(31, 1, (void)0);
#undef PHASE

    // ---- epilogue: tanh + V-dot + 16-lane reduce + atomicAdd ----
    int colb = n0 + wn * 64 + (lane & 15);
    size_t rowg = row0 + (size_t)wm * 128;
    int b = (int)(row0 >> 11);
    float cb = covp[b];
    float vv[4], dp[4];
    #pragma unroll
    for (int n = 0; n < 4; ++n) {
        int c = colb + n * 16;
        vv[n] = V[c];
        dp[n] = decp[b * H_ + c] + cb;
    }
    #pragma unroll
    for (int m = 0; m < 8; ++m) {
        float rs[4] = {0.f, 0.f, 0.f, 0.f};
        #pragma unroll
        for (int n = 0; n < 4; ++n) {
            f32x4 Aq = acc[m][n];
            #pragma unroll
            for (int j = 0; j < 4; ++j) {
                float x = Aq[j] + dp[n];
                float e = __expf(2.f * x);
                float th = 1.f - 2.f / (e + 1.f); // inf-safe tanh
                rs[j] += th * vv[n];
            }
        }
        #pragma unroll
        for (int off = 1; off < 16; off <<= 1) {
            #pragma unroll
            for (int j = 0; j < 4; ++j) rs[j] += __shfl_xor(rs[j], off);
        }
        if ((lane & 15) == 0) {
            size_t r = rowg + m * 16 + (lane >> 4) * 4;
            #pragma unroll
            for (int j = 0; j < 4; ++j) atomicAdd(&scores[r + j], rs[j]);
        }
    }
}

// ---------- fallback epilogue (4-wave kernel) ----------
__device__ __forceinline__ void score_epilogue(
    f32x4 acc[4][4], int n0, int wm, int wn, int lane, size_t row0,
    const float* __restrict__ decp, const float* __restrict__ covp,
    const float* __restrict__ V, float* __restrict__ scores)
{
    int colb = n0 + wn * 64 + (lane & 15);
    size_t rowg = row0 + (size_t)wm * 64;
    int b = (int)(rowg >> 11);
    float cb = covp[b];
    float vv[4], dp[4];
    #pragma unroll
    for (int n = 0; n < 4; ++n) {
        int c = colb + n * 16;
        vv[n] = V[c];
        dp[n] = decp[b * H_ + c] + cb;
    }
    #pragma unroll
    for (int m = 0; m < 4; ++m) {
        float rs[4] = {0.f, 0.f, 0.f, 0.f};
        #pragma unroll
        for (int n = 0; n < 4; ++n) {
            f32x4 A = acc[m][n];
            #pragma unroll
            for (int j = 0; j < 4; ++j) {
                float x = A[j] + dp[n];
                float e = __expf(2.f * x);
                float th = 1.f - 2.f / (e + 1.f);
                rs[j] += th * vv[n];
            }
        }
        #pragma unroll
        for (int off = 1; off < 16; off <<= 1) {
            #pragma unroll
            for (int j = 0; j < 4; ++j) rs[j] += __shfl_xor(rs[j], off);
        }
        if ((lane & 15) == 0) {
            size_t r = rowg + m * 16 + (lane >> 4) * 4;
            #pragma unroll
            for (int j = 0; j < 4; ++j) atomicAdd(&scores[r + j], rs[j]);
        }
    }
}

// ---------- fallback GEMM (fp32 A reg-staged, 128^2) ----------
__global__ __launch_bounds__(256, 2) void k_gemm_stage32(
    const float* __restrict__ enc, const unsigned short* __restrict__ whT,
    const float* __restrict__ decp, const float* __restrict__ covp,
    const float* __restrict__ V, float* __restrict__ scores)
{
    __shared__ uint4 lds[2][1024];
    int bid = blockIdx.x;
    int xcd = bid & 7, idx = bid >> 3;
    int tile_m = xcd * 64 + (idx >> 3);
    int tile_n = idx & 7;
    int t = threadIdx.x, lane = t & 63, wid = t >> 6;
    int wm = wid >> 1, wn = wid & 1;
    size_t row0 = (size_t)tile_m * 128;
    int n0 = tile_n * 128;
    int c0 = t, c1 = t + 256;
    int blk0 = c0 >> 6, l0 = c0 & 63, r0 = blk0 * 16 + (l0 & 15), ks0 = l0 >> 4;
    int blk1 = c1 >> 6, l1 = c1 & 63, r1 = blk1 * 16 + (l1 & 15), ks1 = l1 >> 4;
    const float* pa0 = enc + (row0 + r0) * H_ + ks0 * 8;
    const float* pa1 = enc + (row0 + r1) * H_ + ks1 * 8;
    const unsigned short* pb0 = whT + (size_t)(n0 + r0) * H_ + ks0 * 8;
    const unsigned short* pb1 = whT + (size_t)(n0 + r1) * H_ + ks1 * 8;
    f32x4 acc[4][4] = {};
    float4 a0x, a0y, a1x, a1y;
    uint4 b0, b1;
    auto LOAD = [&](int kt) {
        const float4* q0 = (const float4*)(pa0 + kt * 32);
        a0x = q0[0]; a0y = q0[1];
        const float4* q1 = (const float4*)(pa1 + kt * 32);
        a1x = q1[0]; a1y = q1[1];
        b0 = *(const uint4*)(pb0 + kt * 32);
        b1 = *(const uint4*)(pb1 + kt * 32);
    };
    auto WRITE = [&](int buf) {
        lds[buf][c0] = make_uint4(pk2(a0x.x, a0x.y), pk2(a0x.z, a0x.w),
                                  pk2(a0y.x, a0y.y), pk2(a0y.z, a0y.w));
        lds[buf][c1] = make_uint4(pk2(a1x.x, a1x.y), pk2(a1x.z, a1x.w),
                                  pk2(a1y.x, a1y.y), pk2(a1y.z, a1y.w));
        lds[buf][512 + c0] = b0;
        lds[buf][512 + c1] = b1;
    };
    LOAD(0); WRITE(0); __syncthreads();
    int cur = 0;
    for (int kt = 0; kt < 32; ++kt) {
        if (kt < 31) LOAD(kt + 1);
        const short8* LA = (const short8*)&lds[cur][0];
        const short8* LB = (const short8*)&lds[cur][512];
        short8 af[4], bf[4];
        #pragma unroll
        for (int m = 0; m < 4; ++m) af[m] = LA[(wm * 4 + m) * 64 + lane];
        #pragma unroll
        for (int n = 0; n < 4; ++n) bf[n] = LB[(wn * 4 + n) * 64 + lane];
        #pragma unroll
        for (int m = 0; m < 4; ++m)
            #pragma unroll
            for (int n = 0; n < 4; ++n)
                acc[m][n] = __builtin_amdgcn_mfma_f32_16x16x32_bf16(af[m], bf[n], acc[m][n], 0, 0, 0);
        if (kt < 31) WRITE(cur ^ 1);
        __syncthreads();
        cur ^= 1;
    }
    score_epilogue(acc, n0, wm, wn, lane, row0, decp, covp, V, scores);
}

// ---------- softmax over S per b; writes attn and coverage_new ----------
__global__ void k_softmax(const float* __restrict__ scores, const float* __restrict__ cov,
                          float* __restrict__ out) {
    int b = blockIdx.x, t = threadIdx.x;
    float* attn = out + B_ * H_;
    float* covn = out + B_ * H_ + B_ * S_;
    float v[8];
    float mx = -1e30f;
    #pragma unroll
    for (int i = 0; i < 8; ++i) {
        v[i] = scores[b * S_ + i * 256 + t];
        mx = fmaxf(mx, v[i]);
    }
    for (int off = 32; off; off >>= 1) mx = fmaxf(mx, __shfl_xor(mx, off));
    __shared__ float wsm[4], wss[4];
    if ((t & 63) == 0) wsm[t >> 6] = mx;
    __syncthreads();
    mx = fmaxf(fmaxf(wsm[0], wsm[1]), fmaxf(wsm[2], wsm[3]));
    float sum = 0.f;
    #pragma unroll
    for (int i = 0; i < 8; ++i) { v[i] = __expf(v[i] - mx); sum += v[i]; }
    for (int off = 32; off; off >>= 1) sum += __shfl_xor(sum, off);
    if ((t & 63) == 0) wss[t >> 6] = sum;
    __syncthreads();
    sum = wss[0] + wss[1] + wss[2] + wss[3];
    float inv = 1.f / sum;
    #pragma unroll
    for (int i = 0; i < 8; ++i) {
        int s = i * 256 + t;
        float a = v[i] * inv;
        attn[b * S_ + s] = a;
        covn[b * S_ + s] = cov[b * S_ + s] + a;
    }
}

// ---------- context from bf16 enc ----------
__global__ void k_context_bf(const unsigned short* __restrict__ encBF,
                             const float* __restrict__ attn, float* __restrict__ ctx) {
    int b = blockIdx.y, chunk = blockIdx.x; // 16 chunks x 128 s
    int t = threadIdx.x;
    __shared__ float sa[128];
    int s0 = chunk * 128;
    if (t < 128) sa[t] = attn[b * S_ + s0 + t];
    __syncthreads();
    float4 acc = {0.f, 0.f, 0.f, 0.f};
    const unsigned short* e = encBF + ((size_t)(b * S_ + s0)) * H_ + t * 4;
    #pragma unroll 4
    for (int s = 0; s < 128; ++s) {
        u16x4 x = *(const u16x4*)(e + (size_t)s * H_);
        float a = sa[s];
        acc.x += a * bf2f(x[0]); acc.y += a * bf2f(x[1]);
        acc.z += a * bf2f(x[2]); acc.w += a * bf2f(x[3]);
    }
    float* c = ctx + b * H_ + t * 4;
    atomicAdd(c + 0, acc.x); atomicAdd(c + 1, acc.y);
    atomicAdd(c + 2, acc.z); atomicAdd(c + 3, acc.w);
}

// ---------- context from fp32 enc (fallback) ----------
__global__ void k_context_f32(const float* __restrict__ enc, const float* __restrict__ attn,
                              float* __restrict__ ctx) {
    int b = blockIdx.y, chunk = blockIdx.x;
    int t = threadIdx.x;
    __shared__ float sa[128];
    int s0 = chunk * 128;
    if (t < 128) sa[t] = attn[b * S_ + s0 + t];
    __syncthreads();
    float4 acc = {0.f, 0.f, 0.f, 0.f};
    const float4* e = (const float4*)(enc + ((size_t)b * S_ + s0) * H_) + t;
    #pragma unroll 4
    for (int s = 0; s < 128; ++s) {
        float4 x = e[(size_t)s * (H_ / 4)];
        float a = sa[s];
        acc.x += a * x.x; acc.y += a * x.y; acc.z += a * x.z; acc.w += a * x.w;
    }
    float* c = ctx + b * H_ + t * 4;
    atomicAdd(c + 0, acc.x); atomicAdd(c + 1, acc.y);
    atomicAdd(c + 2, acc.z); atomicAdd(c + 3, acc.w);
}

extern "C" void kernel_launch(void* const* d_in, const int* in_sizes, int n_in,
                              void* d_out, int out_size, void* d_ws, size_t ws_size,
                              hipStream_t stream) {
    (void)in_sizes; (void)n_in; (void)out_size;
    const float* ds  = (const float*)d_in[0];
    const float* enc = (const float*)d_in[1];
    const float* cov = (const float*)d_in[2];
    const float* Wh  = (const float*)d_in[3];
    const float* bh  = (const float*)d_in[4];
    const float* Ws  = (const float*)d_in[5];
    const float* bs  = (const float*)d_in[6];
    const float* V   = (const float*)d_in[7];
    // d_in[8] = bv: softmax-invariant constant -> unused
    const float* Wc  = (const float*)d_in[9];
    const float* bc  = (const float*)d_in[10];
    float* out = (float*)d_out;

    float* ws_scores = (float*)d_ws;                          // 65536 f32
    float* ws_decp   = ws_scores + B_ * S_;                   // 32768 f32
    float* ws_covp   = ws_decp + B_ * H_;                     // 64 f32
    unsigned short* ws_whT = (unsigned short*)(ws_covp + 64); // 1M bf16 (2MB)
    unsigned short* ws_encBF = ws_whT + (size_t)H_ * H_;      // 64M bf16 (128MB)
    const size_t need_full = ((char*)(ws_encBF + (size_t)B_ * S_ * H_)) - (char*)d_ws;

    hipMemsetAsync(ws_scores, 0, B_ * S_ * sizeof(float), stream);
    hipMemsetAsync(ws_decp, 0, B_ * H_ * sizeof(float), stream);  // split-K accumulators
    hipMemsetAsync(out, 0, B_ * H_ * sizeof(float), stream);      // context accumulators

    k_whT<<<dim3(16, 16), dim3(64, 4), 0, stream>>>(Wh, ws_whT);
    k_decp_sk<<<dim3(4, 32, 4), 256, 0, stream>>>(ds, Ws, bs, bh, ws_decp);
    k_covp<<<32, 256, 0, stream>>>(cov, Wc, bc, ws_covp);

    if (ws_size >= need_full) {
        k_cvt<<<2048, 256, 0, stream>>>(enc, (uint4*)ws_encBF, (B_ * S_ * H_) / 8);
        k_gemm_8p<<<1024, 512, 0, stream>>>(ws_encBF, ws_whT, ws_decp, ws_covp, V, ws_scores);
        k_softmax<<<32, 256, 0, stream>>>(ws_scores, cov, out);
        k_context_bf<<<dim3(16, 32), 256, 0, stream>>>(ws_encBF, out + B_ * H_, out);
    } else {
        k_gemm_stage32<<<4096, 256, 0, stream>>>(enc, ws_whT, ws_decp, ws_covp, V, ws_scores);
        k_softmax<<<32, 256, 0, stream>>>(ws_scores, cov, out);
        k_context_f32<<<dim3(16, 32), 256, 0, stream>>>(enc, out + B_ * H_, out);
    }
}